// Round 5
// baseline (243.240 us; speedup 1.0000x reference)
//
#include <hip/hip_runtime.h>

// Fused bilinear-2x-up -> leaky_relu(0.01) -> bilinear-0.5x-down
// == 3x3 clamped-edge stencil per output pixel:
//   up00 = .5625 e + .1875(b+d) + .0625 a   (etc. for the other 3 corners)
//   out  = 0.25 * sum(leaky_relu(up**))
//
// R8: 2x4 tile (R7) + bijective XCD-chunk swizzle.
// R7 post-mortem: FETCH 65->158 MB because the 2x4 decode put py's low bit
// into blockIdx%8 -> adjacent py pairs (which share halo rows) landed on
// different XCDs -> cross-XCD L2 miss on every halo row. Swizzle gives
// XCD k the contiguous logical range [512k,512k+512) = images {2k,2k+1},
// py sequential (px4_hi fastest): halo-row working set ~256 KB per XCD,
// easily L2-resident. (NT stores stay reverted: R5 proved them a 21 us
// regression on the store path.)
//
// Layout: (16,128,128,128) fp32 NHWC; C=128 -> 32 float4 groups, lane takes
// one c4 group: 32 consecutive lanes load 512 B contiguous per (row,col).

#define NEG_SLOPE 0.01f

__device__ __forceinline__ float lrelu(float v) {
    return fmaxf(v, NEG_SLOPE * v);  // slope < 1 => where(v>=0,v,s*v) == max
}

__device__ __forceinline__ float stencil(float a, float b, float c,
                                         float d, float e, float f,
                                         float g, float h, float i) {
    float up00 = 0.5625f * e + 0.1875f * (b + d) + 0.0625f * a;
    float up01 = 0.5625f * e + 0.1875f * (b + f) + 0.0625f * c;
    float up10 = 0.5625f * e + 0.1875f * (d + h) + 0.0625f * g;
    float up11 = 0.5625f * e + 0.1875f * (f + h) + 0.0625f * i;
    return 0.25f * (lrelu(up00) + lrelu(up01) + lrelu(up10) + lrelu(up11));
}

__device__ __forceinline__ float4 stencil4(const float4& a, const float4& b, const float4& c,
                                           const float4& d, const float4& e, const float4& f,
                                           const float4& g, const float4& h, const float4& i) {
    float4 o;
    o.x = stencil(a.x, b.x, c.x, d.x, e.x, f.x, g.x, h.x, i.x);
    o.y = stencil(a.y, b.y, c.y, d.y, e.y, f.y, g.y, h.y, i.y);
    o.z = stencil(a.z, b.z, c.z, d.z, e.z, f.z, g.z, h.z, i.z);
    o.w = stencil(a.w, b.w, c.w, d.w, e.w, f.w, g.w, h.w, i.w);
    return o;
}

__global__ __launch_bounds__(256) void ActivationFilter_kernel(
        const float4* __restrict__ in, float4* __restrict__ out) {
    // XCD-chunk swizzle: 4096 blocks, physical p runs on XCD p%8; logical
    // l = (p%8)*512 + p/8 gives XCD k the contiguous range [512k,512k+512):
    // b = l>>8 in {2k,2k+1}, py = (l>>2)&63 sequential, px4_hi = l&3
    // fastest. Bijective since 4096 % 8 == 0.
    const int p = blockIdx.x;
    const int l = ((p & 7) << 9) + (p >> 3);

    // thread -> (b, y-pair, x-quad, c4): 16 * 64 * 32 * 32 = 1,048,576
    const int t   = (l << 8) + threadIdx.x;
    const int c4  = t & 31;
    const int px4 = (t >> 5) & 31;
    const int py  = (t >> 10) & 63;
    const int b   = t >> 16;

    const int x0 = px4 << 2, y0 = py << 1;
    const int xm = max(x0 - 1, 0), x5 = min(x0 + 4, 127);
    const int ym = max(y0 - 1, 0), y3 = min(y0 + 2, 127);

    const int rb = b << 7;  // b*128
    // float4-unit address of (b, Y, X, c4)
#define ADDR(Y, X) (((((rb + (Y)) << 7) + (X)) << 5) + c4)

    // 4x6 clamped neighborhood:
    // rows {ym, y0, y0+1, y3} x cols {xm, x0, x0+1, x0+2, x0+3, x5}
    const float4 v00 = in[ADDR(ym,   xm)],   v01 = in[ADDR(ym,   x0)],
                 v02 = in[ADDR(ym,   x0+1)], v03 = in[ADDR(ym,   x0+2)],
                 v04 = in[ADDR(ym,   x0+3)], v05 = in[ADDR(ym,   x5)];
    const float4 v10 = in[ADDR(y0,   xm)],   v11 = in[ADDR(y0,   x0)],
                 v12 = in[ADDR(y0,   x0+1)], v13 = in[ADDR(y0,   x0+2)],
                 v14 = in[ADDR(y0,   x0+3)], v15 = in[ADDR(y0,   x5)];
    const float4 v20 = in[ADDR(y0+1, xm)],   v21 = in[ADDR(y0+1, x0)],
                 v22 = in[ADDR(y0+1, x0+1)], v23 = in[ADDR(y0+1, x0+2)],
                 v24 = in[ADDR(y0+1, x0+3)], v25 = in[ADDR(y0+1, x5)];
    const float4 v30 = in[ADDR(y3,   xm)],   v31 = in[ADDR(y3,   x0)],
                 v32 = in[ADDR(y3,   x0+1)], v33 = in[ADDR(y3,   x0+2)],
                 v34 = in[ADDR(y3,   x0+3)], v35 = in[ADDR(y3,   x5)];

    out[ADDR(y0,   x0  )] = stencil4(v00, v01, v02, v10, v11, v12, v20, v21, v22);
    out[ADDR(y0,   x0+1)] = stencil4(v01, v02, v03, v11, v12, v13, v21, v22, v23);
    out[ADDR(y0,   x0+2)] = stencil4(v02, v03, v04, v12, v13, v14, v22, v23, v24);
    out[ADDR(y0,   x0+3)] = stencil4(v03, v04, v05, v13, v14, v15, v23, v24, v25);
    out[ADDR(y0+1, x0  )] = stencil4(v10, v11, v12, v20, v21, v22, v30, v31, v32);
    out[ADDR(y0+1, x0+1)] = stencil4(v11, v12, v13, v21, v22, v23, v31, v32, v33);
    out[ADDR(y0+1, x0+2)] = stencil4(v12, v13, v14, v22, v23, v24, v32, v33, v34);
    out[ADDR(y0+1, x0+3)] = stencil4(v13, v14, v15, v23, v24, v25, v33, v34, v35);
#undef ADDR
}

extern "C" void kernel_launch(void* const* d_in, const int* in_sizes, int n_in,
                              void* d_out, int out_size, void* d_ws, size_t ws_size,
                              hipStream_t stream) {
    const float4* in = (const float4*)d_in[0];
    float4* out = (float4*)d_out;
    // 1,048,576 threads -> 4096 blocks of 256
    ActivationFilter_kernel<<<dim3(4096), dim3(256), 0, stream>>>(in, out);
}

// Round 6
// 225.131 us; speedup vs baseline: 1.0804x; 1.0804x over previous
//
#include <hip/hip_runtime.h>

// Fused bilinear-2x-up -> leaky_relu(0.01) -> bilinear-0.5x-down
// == 3x3 clamped-edge stencil per output pixel:
//   up00 = .5625 e + .1875(b+d) + .0625 a   (etc. for the other 3 corners)
//   out  = 0.25 * sum(leaky_relu(up**))
//
// R9: LDS-staged halo. Ladder so far: R3 2x2 straight-line = 63 us;
// NT stores = +21 us (revert); 2x4 tile = +19 us (revert); XCD swizzles =
// fetch-neutral-to-better but time-neutral-to-worse (revert). Counters say
// latency/queue-bound (2.5-3.6 TB/s HBM, VALU 30%, 0 conflicts), and
// cutting HBM fetch 67 MB bought zero time -> the limiter is VMEM request
// count, not bytes. 2x2 straight-line issues 16 requests/thread for 9
// distinct values (x1.78 redundant).
//
// This round: block (2 rows x 16 cols x 128 ch output) stages its
// 4 x 18 x 32-c4 input neighborhood (36 KB) into LDS with 9 coalesced
// loads/thread (-44% global requests), one barrier, then 16 contiguous
// ds_read_b128/thread feed the same straight-line stencil math.
//
// Layout: (16,128,128,128) fp32 NHWC; C=128 -> 32 float4 groups.

#define NEG_SLOPE 0.01f

__device__ __forceinline__ float lrelu(float v) {
    return fmaxf(v, NEG_SLOPE * v);  // slope < 1 => where(v>=0,v,s*v) == max
}

__device__ __forceinline__ float stencil(float a, float b, float c,
                                         float d, float e, float f,
                                         float g, float h, float i) {
    float up00 = 0.5625f * e + 0.1875f * (b + d) + 0.0625f * a;
    float up01 = 0.5625f * e + 0.1875f * (b + f) + 0.0625f * c;
    float up10 = 0.5625f * e + 0.1875f * (d + h) + 0.0625f * g;
    float up11 = 0.5625f * e + 0.1875f * (f + h) + 0.0625f * i;
    return 0.25f * (lrelu(up00) + lrelu(up01) + lrelu(up10) + lrelu(up11));
}

__device__ __forceinline__ float4 stencil4(const float4& a, const float4& b, const float4& c,
                                           const float4& d, const float4& e, const float4& f,
                                           const float4& g, const float4& h, const float4& i) {
    float4 o;
    o.x = stencil(a.x, b.x, c.x, d.x, e.x, f.x, g.x, h.x, i.x);
    o.y = stencil(a.y, b.y, c.y, d.y, e.y, f.y, g.y, h.y, i.y);
    o.z = stencil(a.z, b.z, c.z, d.z, e.z, f.z, g.z, h.z, i.z);
    o.w = stencil(a.w, b.w, c.w, d.w, e.w, f.w, g.w, h.w, i.w);
    return o;
}

__global__ __launch_bounds__(256) void ActivationFilter_kernel(
        const float4* __restrict__ in, float4* __restrict__ out) {
    // Block tile (same decode as the 63us R3 mapping, factored per-block):
    // blk bits: [0:2]=px_hi (x-strip of 16), [3:8]=py, [9:12]=b.
    __shared__ float4 lds[4][18][32];   // [row][col][c4] = 36 KB

    const int tid = threadIdx.x;
    const int blk = blockIdx.x;
    const int xs  = (blk & 7) << 4;       // x start of the 16-col strip
    const int py  = (blk >> 3) & 63;
    const int b   = blk >> 9;
    const int y0  = py << 1;
    const int rb  = b << 7;               // b*128

    // ---- stage 4 rows x 18 cols x 32 c4 = 2304 float4 (9 per thread) ----
    // LDS row r holds global row clamp(y0-1+r); LDS col j holds global col
    // clamp(xs-1+j). Consecutive idx -> consecutive c4 -> coalesced 512 B.
    float4* lf = &lds[0][0][0];
#pragma unroll
    for (int k = 0; k < 9; ++k) {
        const int idx  = tid + (k << 8);        // 0..2303
        const int r    = idx / 576;             // 576 = 18*32
        const int rem  = idx - r * 576;
        const int xcol = rem >> 5;
        const int c    = rem & 31;
        const int row  = min(max(y0 - 1 + r, 0), 127);
        const int col  = min(max(xs - 1 + xcol, 0), 127);
        lf[idx] = in[((((rb + row) << 7) + col) << 5) + c];
    }
    __syncthreads();

    // ---- compute 2x2 outputs per thread from LDS ----
    const int c4 = tid & 31;
    const int pl = tid >> 5;              // 0..7: which px-pair in the strip
    const int x0 = xs + (pl << 1);
    const int j0 = pl << 1;               // LDS col of x0-1 (clamped)

    const float4 v00 = lds[0][j0][c4], v01 = lds[0][j0+1][c4],
                 v02 = lds[0][j0+2][c4], v03 = lds[0][j0+3][c4];
    const float4 v10 = lds[1][j0][c4], v11 = lds[1][j0+1][c4],
                 v12 = lds[1][j0+2][c4], v13 = lds[1][j0+3][c4];
    const float4 v20 = lds[2][j0][c4], v21 = lds[2][j0+1][c4],
                 v22 = lds[2][j0+2][c4], v23 = lds[2][j0+3][c4];
    const float4 v30 = lds[3][j0][c4], v31 = lds[3][j0+1][c4],
                 v32 = lds[3][j0+2][c4], v33 = lds[3][j0+3][c4];

    // float4-unit address of (b, Y, X, c4)
#define ADDR(Y, X) (((((rb + (Y)) << 7) + (X)) << 5) + c4)
    out[ADDR(y0,   x0  )] = stencil4(v00, v01, v02, v10, v11, v12, v20, v21, v22);
    out[ADDR(y0,   x0+1)] = stencil4(v01, v02, v03, v11, v12, v13, v21, v22, v23);
    out[ADDR(y0+1, x0  )] = stencil4(v10, v11, v12, v20, v21, v22, v30, v31, v32);
    out[ADDR(y0+1, x0+1)] = stencil4(v11, v12, v13, v21, v22, v23, v31, v32, v33);
#undef ADDR
}

extern "C" void kernel_launch(void* const* d_in, const int* in_sizes, int n_in,
                              void* d_out, int out_size, void* d_ws, size_t ws_size,
                              hipStream_t stream) {
    const float4* in = (const float4*)d_in[0];
    float4* out = (float4*)d_out;
    // 2,097,152 threads -> 8192 blocks of 256
    ActivationFilter_kernel<<<dim3(8192), dim3(256), 0, stream>>>(in, out);
}